// Round 11
// baseline (382.573 us; speedup 1.0000x reference)
//
#include <hip/hip_runtime.h>

#define F_IN 256
#define H1 128
#define H2 32
#define BN_EPS 1e-5f
#define BSHIFT 8
#define BCAP 16384
#define CHUNK 4096
#define NSHARD 8
#define AGG1_GRID 1792

typedef short bf16x8 __attribute__((ext_vector_type(8)));
typedef float f32x4 __attribute__((ext_vector_type(4)));

__device__ __forceinline__ ushort f2bf(float f) {
    uint u = __float_as_uint(f);
    return (ushort)((u + 0x7FFFu + ((u >> 16) & 1u)) >> 16);
}
__device__ __forceinline__ float bf2f(ushort h) {
    return __uint_as_float((uint)h << 16);
}
__device__ __forceinline__ uint pack2(float a, float b) {
    return (uint)f2bf(a) | ((uint)f2bf(b) << 16);
}
__device__ __forceinline__ void unpack2(uint u, float& a, float& b) {
    a = __uint_as_float(u << 16);
    b = __uint_as_float(u & 0xFFFF0000u);
}
__device__ __forceinline__ int clampN(int v, int N) {
    return v < 0 ? 0 : (v >= N ? N - 1 : v);
}

// ---------------------------------------------------------------------------
// super0: weight transpose+cast (blocks 0..211) + zero scratch (block 212)
// ---------------------------------------------------------------------------
__global__ __launch_bounds__(256) void super0_k(
    const float* __restrict__ W1a, const float* __restrict__ W1b,
    const float* __restrict__ W2a, const float* __restrict__ W2b,
    ushort* __restrict__ w1aT, ushort* __restrict__ w1bT,
    ushort* __restrict__ w2aT, ushort* __restrict__ w2bT,
    int* __restrict__ bucket_cursor, float* __restrict__ sums1,
    float* __restrict__ sums2) {
    const int tid = threadIdx.x;
    if (blockIdx.x == 212) {
        for (int i = tid; i < 512; i += 256) bucket_cursor[i] = 0;
        for (int i = tid; i < NSHARD * 2 * H1; i += 256) sums1[i] = 0.f;
        for (int i = tid; i < NSHARD * 2 * H2; i += 256) sums2[i] = 0.f;
        return;
    }
    int idx = blockIdx.x * 256 + tid;
    if (idx < 32768) {                // 256x128
        int k = idx >> 7, c = idx & 127;
        w1aT[c * 256 + k] = f2bf(W1a[idx]);
    } else if (idx < 49152) {         // 128x128
        int t = idx - 32768;
        int k = t >> 7, c = t & 127;
        w1bT[c * 128 + k] = f2bf(W1b[t]);
    } else if (idx < 53248) {         // 128x32
        int t = idx - 49152;
        int k = t >> 5, c = t & 31;
        w2aT[c * 128 + k] = f2bf(W2a[t]);
    } else if (idx < 54272) {         // 32x32
        int t = idx - 53248;
        int k = t >> 5, c = t & 31;
        w2bT[c * 32 + k] = f2bf(W2b[t]);
    }
}

// ---------------------------------------------------------------------------
// binA (staged): CHUNK edges through LDS; per-chunk histogram -> one global
// atomic per (chunk,bucket); grouped record writes.
// record = src (17b) | dst_low (8b) << 17.
// ---------------------------------------------------------------------------
__global__ __launch_bounds__(256) void binA_k(const int* __restrict__ eb,
                                              int E, int N, int NBUCK,
                                              int* __restrict__ bucket_cursor,
                                              uint* __restrict__ rec) {
    __shared__ int lcnt[512];
    __shared__ int lbase[512];
    __shared__ uint lrec[CHUNK];
    __shared__ ushort lbk[CHUNK];
    __shared__ ushort lrk[CHUNK];
    __shared__ int nzf;
    const int tid = threadIdx.x;
    const int cbase = blockIdx.x * CHUNK;
    const int cnum = min(CHUNK, E - cbase);
    if (cnum <= 0) return;
    if (tid == 0) nzf = 0;
    __syncthreads();
    {   // sample odd words of this chunk: int64 -> all high halves zero
        int i = tid * (CHUNK / 256);
        if (i < cnum && eb[2 * (cbase + i) + 1] != 0) atomicAdd(&nzf, 1);
    }
    for (int i = tid; i < NBUCK; i += 256) lcnt[i] = 0;
    __syncthreads();
    const int is64 = (nzf == 0);
    for (int i = tid; i < cnum; i += 256) {
        int e = cbase + i;
        int s = is64 ? eb[2 * e] : eb[e];
        int d = is64 ? eb[2 * (E + e)] : eb[E + e];
        s = clampN(s, N);
        d = clampN(d, N);
        int bk = d >> BSHIFT;
        int rk = atomicAdd(&lcnt[bk], 1);
        lrec[i] = (uint)s | ((uint)(d & 255) << 17);
        lbk[i] = (ushort)bk;
        lrk[i] = (ushort)rk;
    }
    __syncthreads();
    for (int i = tid; i < NBUCK; i += 256)
        if (lcnt[i]) lbase[i] = atomicAdd(&bucket_cursor[i], lcnt[i]);
    __syncthreads();
    for (int i = tid; i < cnum; i += 256) {
        int bk = lbk[i];
        int pos = lbase[bk] + lrk[i];
        if (pos < BCAP) rec[(size_t)bk * BCAP + pos] = lrec[i];
    }
}

// ---------------------------------------------------------------------------
// binB body: one block per dst-bucket. Bins records by (dst_low, src-octile)
// = 2048 bins -> LDS scan -> rs2 boundaries + esrc grouped by (node, octile).
// ---------------------------------------------------------------------------
__device__ __forceinline__ void binB_body(int bk, const uint* __restrict__ rec,
                                          const int* __restrict__ bucket_cursor,
                                          int N, int NBUCK,
                                          int* __restrict__ rs2,
                                          int* __restrict__ esrc) {
    __shared__ int cnt[2048];
    __shared__ int rnk[2048];
    __shared__ int red[256];
    const int tid = threadIdx.x;
    int part = 0;
    for (int i = tid; i < bk; i += 256) {
        int c = bucket_cursor[i];
        part += (c < BCAP) ? c : BCAP;
    }
    red[tid] = part;
    __syncthreads();
    for (int s = 128; s > 0; s >>= 1) {
        if (tid < s) red[tid] += red[tid + s];
        __syncthreads();
    }
    const int base = red[0];
    __syncthreads();
    int cntb = bucket_cursor[bk];
    if (cntb > BCAP) cntb = BCAP;
    if (bk == NBUCK - 1 && tid == 0) rs2[(size_t)N * 8] = base + cntb;

    const uint* r = rec + (size_t)bk * BCAP;
    for (int i = tid; i < 2048; i += 256) { cnt[i] = 0; rnk[i] = 0; }
    __syncthreads();
    for (int i = tid; i < cntb; i += 256) {
        uint rv = r[i];
        atomicAdd(&cnt[((rv >> 17) << 3) | ((rv >> 14) & 7u)], 1);
    }
    __syncthreads();
    int loc[8];
    int s = 0;
#pragma unroll
    for (int j = 0; j < 8; ++j) { loc[j] = s; s += cnt[tid * 8 + j]; }
    const int tot = s;
    red[tid] = tot;
    __syncthreads();
    for (int off = 1; off < 256; off <<= 1) {
        int t = (tid >= off) ? red[tid - off] : 0;
        __syncthreads();
        red[tid] += t;
        __syncthreads();
    }
    const int excl_t = red[tid] - tot;
    __syncthreads();
    const int n0 = bk << BSHIFT;
#pragma unroll
    for (int j = 0; j < 8; ++j) {
        int b = tid * 8 + j;
        int ex = excl_t + loc[j];
        cnt[b] = ex;
        int node = n0 + (b >> 3);
        if (node < N) rs2[(size_t)node * 8 + (b & 7)] = base + ex;
    }
    __syncthreads();
    for (int i = tid; i < cntb; i += 256) {
        uint rv = r[i];
        int b = ((rv >> 17) << 3) | ((rv >> 14) & 7u);
        int pos = cnt[b] + atomicAdd(&rnk[b], 1);
        esrc[base + pos] = (int)(rv & 0x1FFFFu);
    }
}

// ---------------------------------------------------------------------------
// gemm1 body: t1 = x(f32, packed in-register) @ W1aT, bf16 out. No LDS.
// ---------------------------------------------------------------------------
__device__ __forceinline__ void gemm1_body(int bid, const float* __restrict__ Af,
                                           const ushort* __restrict__ WT,
                                           ushort* __restrict__ outb, int N) {
    constexpr int K = F_IN, NC = H1, NF = NC / 16;
    const int lane = threadIdx.x & 63;
    const int wave = threadIdx.x >> 6;
    const int row0 = bid * 64 + wave * 16;
    const int col = lane & 15;
    const int k0 = (lane >> 4) * 8;
    int arow = row0 + col;
    if (arow >= N) arow = N - 1;

    f32x4 acc[NF];
#pragma unroll
    for (int f = 0; f < NF; ++f) acc[f] = (f32x4){0.f, 0.f, 0.f, 0.f};
#pragma unroll
    for (int kc = 0; kc < K; kc += 32) {
        const float* ap = &Af[(size_t)arow * K + kc + k0];
        float4 p = *(const float4*)ap;
        float4 q = *(const float4*)(ap + 4);
        bf16x8 af;
        af[0] = (short)f2bf(p.x); af[1] = (short)f2bf(p.y);
        af[2] = (short)f2bf(p.z); af[3] = (short)f2bf(p.w);
        af[4] = (short)f2bf(q.x); af[5] = (short)f2bf(q.y);
        af[6] = (short)f2bf(q.z); af[7] = (short)f2bf(q.w);
#pragma unroll
        for (int f = 0; f < NF; ++f) {
            bf16x8 bf = *(const bf16x8*)&WT[(size_t)(f * 16 + col) * K + kc + k0];
            acc[f] = __builtin_amdgcn_mfma_f32_16x16x32_bf16(af, bf, acc[f], 0, 0, 0);
        }
    }
    const int crow = row0 + (lane >> 4) * 4;
#pragma unroll
    for (int f = 0; f < NF; ++f) {
        const int c = f * 16 + col;
#pragma unroll
        for (int j = 0; j < 4; ++j) {
            int rr = crow + j;
            if (rr < N) outb[(size_t)rr * NC + c] = f2bf(acc[f][j]);
        }
    }
}

// super2: binB blocks [0, NBUCK) overlap gemm1 blocks [NBUCK, NBUCK+G1).
__global__ __launch_bounds__(256) void super2_k(
    const uint* __restrict__ rec, const int* __restrict__ bucket_cursor,
    int N, int NBUCK, int* __restrict__ rs2, int* __restrict__ esrc,
    const float* __restrict__ x, const ushort* __restrict__ w1aT,
    ushort* __restrict__ t1b) {
    if ((int)blockIdx.x < NBUCK)
        binB_body(blockIdx.x, rec, bucket_cursor, N, NBUCK, rs2, esrc);
    else
        gemm1_body(blockIdx.x - NBUCK, x, w1aT, t1b, N);
}

// ---------------------------------------------------------------------------
// shared GEMM epilogue: store + optional fused column stats
// ---------------------------------------------------------------------------
template <int NC, bool BIAS, bool OUT_BF16, bool STATS, int NF>
__device__ __forceinline__ void gemm_epilogue(f32x4* acc, const float* bias,
                                              void* outv, int N, int row0,
                                              int lane, float* sums) {
    __shared__ float ssum[NC];
    __shared__ float ssq[NC];
    if (STATS) {
        if (threadIdx.x < NC) { ssum[threadIdx.x] = 0.f; ssq[threadIdx.x] = 0.f; }
        __syncthreads();
    }
    const int col0 = lane & 15;
    const int crow = row0 + (lane >> 4) * 4;
#pragma unroll
    for (int f = 0; f < NF; ++f) {
        const int c = f * 16 + col0;
        float bv = BIAS ? bias[c] : 0.f;
        float sv = 0.f, qv = 0.f;
#pragma unroll
        for (int j = 0; j < 4; ++j) {
            int rr = crow + j;
            if (rr < N) {
                float v = acc[f][j] + bv;
                if (OUT_BF16) ((ushort*)outv)[(size_t)rr * NC + c] = f2bf(v);
                else          ((float*)outv)[(size_t)rr * NC + c] = v;
                if (STATS) { sv += v; qv += v * v; }
            }
        }
        if (STATS) {
            sv += __shfl_xor(sv, 16); sv += __shfl_xor(sv, 32);
            qv += __shfl_xor(qv, 16); qv += __shfl_xor(qv, 32);
            if ((lane >> 4) == 0) {
                atomicAdd(&ssum[c], sv);
                atomicAdd(&ssq[c], qv);
            }
        }
    }
    if (STATS) {
        __syncthreads();
        if (threadIdx.x < NC) {
            float* sh = sums + (blockIdx.x & (NSHARD - 1)) * 2 * NC;
            atomicAdd(&sh[threadIdx.x], ssum[threadIdx.x]);
            atomicAdd(&sh[NC + threadIdx.x], ssq[threadIdx.x]);
        }
    }
}

// MFMA GEMM, bf16 A: out[N,NC] = A[N,K] @ WT[NC,K]^T (+bias) [+col stats]
template <int K, int NC, bool BIAS, bool OUT_BF16, bool STATS>
__global__ __launch_bounds__(256) void gemm_mfma_k(const ushort* __restrict__ A,
                                                   const ushort* __restrict__ WT,
                                                   const float* __restrict__ bias,
                                                   void* __restrict__ outv, int N,
                                                   float* __restrict__ sums) {
    constexpr int NF = NC / 16;
    const int lane = threadIdx.x & 63;
    const int wave = threadIdx.x >> 6;
    const int row0 = blockIdx.x * 64 + wave * 16;
    const int col = lane & 15;
    const int k0 = (lane >> 4) * 8;
    int arow = row0 + col;
    if (arow >= N) arow = N - 1;

    f32x4 acc[NF];
#pragma unroll
    for (int f = 0; f < NF; ++f) acc[f] = (f32x4){0.f, 0.f, 0.f, 0.f};
#pragma unroll
    for (int kc = 0; kc < K; kc += 32) {
        bf16x8 af = *(const bf16x8*)&A[(size_t)arow * K + kc + k0];
#pragma unroll
        for (int f = 0; f < NF; ++f) {
            bf16x8 bf = *(const bf16x8*)&WT[(size_t)(f * 16 + col) * K + kc + k0];
            acc[f] = __builtin_amdgcn_mfma_f32_16x16x32_bf16(af, bf, acc[f], 0, 0, 0);
        }
    }
    gemm_epilogue<NC, BIAS, OUT_BF16, STATS, NF>(acc, bias, outv, N, row0, lane, sums);
}

// MFMA GEMM with fused BN finalize (from sharded sums) + BN-apply+ReLU on A
template <int K, int NC, bool OUT_BF16>
__global__ __launch_bounds__(256) void gemm_mfma_bnA_k(const ushort* __restrict__ U,
                                                       const ushort* __restrict__ WT,
                                                       const float* __restrict__ sums,
                                                       const float* __restrict__ g,
                                                       const float* __restrict__ be,
                                                       int Nbn,
                                                       void* __restrict__ outv, int N) {
    constexpr int NF = NC / 16;
    __shared__ __align__(16) float lsc[K];
    __shared__ __align__(16) float lsh[K];
    const int tid = threadIdx.x;
    if (tid < K) {
        float s = 0.f, q = 0.f;
#pragma unroll
        for (int sh = 0; sh < NSHARD; ++sh) {
            s += sums[sh * 2 * K + tid];
            q += sums[sh * 2 * K + K + tid];
        }
        float inv_n = 1.f / (float)Nbn;
        float mean = s * inv_n;
        float var = q * inv_n - mean * mean;
        float sc = g[tid] * rsqrtf(var + BN_EPS);
        lsc[tid] = sc;
        lsh[tid] = be[tid] - mean * sc;
    }
    __syncthreads();

    const int lane = tid & 63;
    const int wave = tid >> 6;
    const int row0 = blockIdx.x * 64 + wave * 16;
    const int col = lane & 15;
    const int k0 = (lane >> 4) * 8;
    int arow = row0 + col;
    if (arow >= N) arow = N - 1;

    f32x4 acc[NF];
#pragma unroll
    for (int f = 0; f < NF; ++f) acc[f] = (f32x4){0.f, 0.f, 0.f, 0.f};
#pragma unroll
    for (int kc = 0; kc < K; kc += 32) {
        bf16x8 raw = *(const bf16x8*)&U[(size_t)arow * K + kc + k0];
        float4 c0 = *(const float4*)&lsc[kc + k0];
        float4 c1 = *(const float4*)&lsc[kc + k0 + 4];
        float4 h0 = *(const float4*)&lsh[kc + k0];
        float4 h1 = *(const float4*)&lsh[kc + k0 + 4];
        bf16x8 af;
        af[0] = (short)f2bf(fmaxf(bf2f((ushort)raw[0]) * c0.x + h0.x, 0.f));
        af[1] = (short)f2bf(fmaxf(bf2f((ushort)raw[1]) * c0.y + h0.y, 0.f));
        af[2] = (short)f2bf(fmaxf(bf2f((ushort)raw[2]) * c0.z + h0.z, 0.f));
        af[3] = (short)f2bf(fmaxf(bf2f((ushort)raw[3]) * c0.w + h0.w, 0.f));
        af[4] = (short)f2bf(fmaxf(bf2f((ushort)raw[4]) * c1.x + h1.x, 0.f));
        af[5] = (short)f2bf(fmaxf(bf2f((ushort)raw[5]) * c1.y + h1.y, 0.f));
        af[6] = (short)f2bf(fmaxf(bf2f((ushort)raw[6]) * c1.z + h1.z, 0.f));
        af[7] = (short)f2bf(fmaxf(bf2f((ushort)raw[7]) * c1.w + h1.w, 0.f));
#pragma unroll
        for (int f = 0; f < NF; ++f) {
            bf16x8 bf = *(const bf16x8*)&WT[(size_t)(f * 16 + col) * K + kc + k0];
            acc[f] = __builtin_amdgcn_mfma_f32_16x16x32_bf16(af, bf, acc[f], 0, 0, 0);
        }
    }
    gemm_epilogue<NC, false, OUT_BF16, false, NF>(acc, nullptr, outv, N, row0, lane, nullptr);
}

// ---------------------------------------------------------------------------
// agg1, phase-coherent WITH deep gather pipeline:
// grid-resident (1792 blocks, 7 blocks/CU); half-wave owns NPH=7 nodes with
// register accumulators. Outer loop = 4 phases (src quartiles via rs2
// octile boundaries): all resident half-waves sweep the same 6.4MB window.
// Within each (node,phase) segment (~8 edges): 8/4/1 unrolled load cascade
// keeps up to 8 gathers in flight (R7's proven MLP).
// ---------------------------------------------------------------------------
__global__ __launch_bounds__(256, 7) void agg_f128b_k(
    const ushort* __restrict__ T, const int* __restrict__ rs2,
    const int* __restrict__ esrc, const float* __restrict__ bias,
    ushort* __restrict__ out, int N, int NPH) {
    const int hw = blockIdx.x * 8 + (threadIdx.x >> 5);
    const int lane = threadIdx.x & 31;
    const int nbase = hw * NPH;
    if (nbase >= N) return;
    const uint2* T2 = (const uint2*)T;
    f32x4 acc[7];
#pragma unroll
    for (int j = 0; j < 7; ++j) acc[j] = (f32x4){0.f, 0.f, 0.f, 0.f};

    for (int ph = 0; ph < 4; ++ph) {
#pragma unroll
        for (int j = 0; j < 7; ++j) {
            int node = nbase + j;
            if (j < NPH && node < N) {
                int p = rs2[(size_t)node * 8 + ph * 2];
                const int pe = rs2[(size_t)node * 8 + ph * 2 + 2];
                float a0 = acc[j][0], a1 = acc[j][1], a2 = acc[j][2], a3 = acc[j][3];
                for (; p + 7 < pe; p += 8) {
                    int s0 = esrc[p],     s1 = esrc[p + 1], s2 = esrc[p + 2], s3 = esrc[p + 3];
                    int s4 = esrc[p + 4], s5 = esrc[p + 5], s6 = esrc[p + 6], s7 = esrc[p + 7];
                    uint2 v0 = T2[(size_t)s0 * 32 + lane];
                    uint2 v1 = T2[(size_t)s1 * 32 + lane];
                    uint2 v2 = T2[(size_t)s2 * 32 + lane];
                    uint2 v3 = T2[(size_t)s3 * 32 + lane];
                    uint2 v4 = T2[(size_t)s4 * 32 + lane];
                    uint2 v5 = T2[(size_t)s5 * 32 + lane];
                    uint2 v6 = T2[(size_t)s6 * 32 + lane];
                    uint2 v7 = T2[(size_t)s7 * 32 + lane];
                    float x0, x1, x2, x3;
                    unpack2(v0.x, x0, x1); unpack2(v0.y, x2, x3);
                    a0 += x0; a1 += x1; a2 += x2; a3 += x3;
                    unpack2(v1.x, x0, x1); unpack2(v1.y, x2, x3);
                    a0 += x0; a1 += x1; a2 += x2; a3 += x3;
                    unpack2(v2.x, x0, x1); unpack2(v2.y, x2, x3);
                    a0 += x0; a1 += x1; a2 += x2; a3 += x3;
                    unpack2(v3.x, x0, x1); unpack2(v3.y, x2, x3);
                    a0 += x0; a1 += x1; a2 += x2; a3 += x3;
                    unpack2(v4.x, x0, x1); unpack2(v4.y, x2, x3);
                    a0 += x0; a1 += x1; a2 += x2; a3 += x3;
                    unpack2(v5.x, x0, x1); unpack2(v5.y, x2, x3);
                    a0 += x0; a1 += x1; a2 += x2; a3 += x3;
                    unpack2(v6.x, x0, x1); unpack2(v6.y, x2, x3);
                    a0 += x0; a1 += x1; a2 += x2; a3 += x3;
                    unpack2(v7.x, x0, x1); unpack2(v7.y, x2, x3);
                    a0 += x0; a1 += x1; a2 += x2; a3 += x3;
                }
                if (p + 3 < pe) {
                    int s0 = esrc[p], s1 = esrc[p + 1], s2 = esrc[p + 2], s3 = esrc[p + 3];
                    uint2 v0 = T2[(size_t)s0 * 32 + lane];
                    uint2 v1 = T2[(size_t)s1 * 32 + lane];
                    uint2 v2 = T2[(size_t)s2 * 32 + lane];
                    uint2 v3 = T2[(size_t)s3 * 32 + lane];
                    float x0, x1, x2, x3;
                    unpack2(v0.x, x0, x1); unpack2(v0.y, x2, x3);
                    a0 += x0; a1 += x1; a2 += x2; a3 += x3;
                    unpack2(v1.x, x0, x1); unpack2(v1.y, x2, x3);
                    a0 += x0; a1 += x1; a2 += x2; a3 += x3;
                    unpack2(v2.x, x0, x1); unpack2(v2.y, x2, x3);
                    a0 += x0; a1 += x1; a2 += x2; a3 += x3;
                    unpack2(v3.x, x0, x1); unpack2(v3.y, x2, x3);
                    a0 += x0; a1 += x1; a2 += x2; a3 += x3;
                    p += 4;
                }
                for (; p < pe; ++p) {
                    uint2 v = T2[(size_t)esrc[p] * 32 + lane];
                    float x0, x1, x2, x3;
                    unpack2(v.x, x0, x1); unpack2(v.y, x2, x3);
                    a0 += x0; a1 += x1; a2 += x2; a3 += x3;
                }
                acc[j][0] = a0; acc[j][1] = a1; acc[j][2] = a2; acc[j][3] = a3;
            }
        }
    }
    const float4 b = ((const float4*)bias)[lane];
#pragma unroll
    for (int j = 0; j < 7; ++j) {
        int node = nbase + j;
        if (j < NPH && node < N) {
            uint2 sv = T2[(size_t)node * 32 + lane];
            float s0, s1, s2, s3;
            unpack2(sv.x, s0, s1); unpack2(sv.y, s2, s3);
            float o0 = fmaxf(acc[j][0] + s0 + b.x, 0.f);
            float o1 = fmaxf(acc[j][1] + s1 + b.y, 0.f);
            float o2 = fmaxf(acc[j][2] + s2 + b.z, 0.f);
            float o3 = fmaxf(acc[j][3] + s3 + b.w, 0.f);
            ((uint2*)out)[(size_t)node * 32 + lane] = make_uint2(pack2(o0, o1), pack2(o2, o3));
        }
    }
}

// F=32: wave per node; 8 neighbor-groups x 8 lanes; cross-group shfl reduce.
__global__ void agg_f32b_k(const ushort* __restrict__ T, const int* __restrict__ rs2,
                           const int* __restrict__ esrc, const float* __restrict__ bias,
                           ushort* __restrict__ out, int N) {
    const int wid = (blockIdx.x << 2) | (threadIdx.x >> 6);
    const int lane = threadIdx.x & 63;
    const int g = lane >> 3, l8 = lane & 7;
    if (wid >= N) return;
    const uint2* T2 = (const uint2*)T;
    float a0 = 0.f, a1 = 0.f, a2 = 0.f, a3 = 0.f;
    const int p0 = rs2[(size_t)wid * 8];
    const int pe = rs2[(size_t)wid * 8 + 8];
    for (int p = p0 + g; p < pe; p += 8) {
        uint2 v = T2[(size_t)esrc[p] * 8 + l8];
        float x0, x1, x2, x3;
        unpack2(v.x, x0, x1); unpack2(v.y, x2, x3);
        a0 += x0; a1 += x1; a2 += x2; a3 += x3;
    }
#pragma unroll
    for (int off = 8; off < 64; off <<= 1) {
        a0 += __shfl_xor(a0, off);
        a1 += __shfl_xor(a1, off);
        a2 += __shfl_xor(a2, off);
        a3 += __shfl_xor(a3, off);
    }
    if (g == 0) {
        uint2 sv = T2[(size_t)wid * 8 + l8];
        float s0, s1, s2, s3;
        unpack2(sv.x, s0, s1); unpack2(sv.y, s2, s3);
        const float4 b = ((const float4*)bias)[l8];
        a0 = fmaxf(a0 + s0 + b.x, 0.f);
        a1 = fmaxf(a1 + s1 + b.y, 0.f);
        a2 = fmaxf(a2 + s2 + b.z, 0.f);
        a3 = fmaxf(a3 + s3 + b.w, 0.f);
        ((uint2*)out)[(size_t)wid * 8 + l8] = make_uint2(pack2(a0, a1), pack2(a2, a3));
    }
}

// ---------------------------------------------------------------------------
// bnapply with fused finalize (from sharded sums): f32 in -> f32 out
// ---------------------------------------------------------------------------
template <int F>
__global__ void bnapply_fin_k(const float* __restrict__ U, const float* __restrict__ sums,
                              const float* __restrict__ g, const float* __restrict__ be,
                              int Nbn, float* __restrict__ out, int total4) {
    __shared__ __align__(16) float lsc[F];
    __shared__ __align__(16) float lsh[F];
    const int tid = threadIdx.x;
    if (tid < F) {
        float s = 0.f, q = 0.f;
#pragma unroll
        for (int sh = 0; sh < NSHARD; ++sh) {
            s += sums[sh * 2 * F + tid];
            q += sums[sh * 2 * F + F + tid];
        }
        float inv_n = 1.f / (float)Nbn;
        float mean = s * inv_n;
        float var = q * inv_n - mean * mean;
        float sc = g[tid] * rsqrtf(var + BN_EPS);
        lsc[tid] = sc;
        lsh[tid] = be[tid] - mean * sc;
    }
    __syncthreads();
    const float4* U4 = (const float4*)U;
    float4* O4 = (float4*)out;
    const int stride = gridDim.x * blockDim.x;
    for (int i = blockIdx.x * blockDim.x + tid; i < total4; i += stride) {
        int c4 = (i % (F / 4)) * 4;
        float4 u = U4[i];
        float4 sc = *(const float4*)&lsc[c4];
        float4 sh = *(const float4*)&lsh[c4];
        float4 o;
        o.x = fmaxf(u.x * sc.x + sh.x, 0.f);
        o.y = fmaxf(u.y * sc.y + sh.y, 0.f);
        o.z = fmaxf(u.z * sc.z + sh.z, 0.f);
        o.w = fmaxf(u.w * sc.w + sh.w, 0.f);
        O4[i] = o;
    }
}

// ---------------------------------------------------------------------------
extern "C" void kernel_launch(void* const* d_in, const int* in_sizes, int n_in,
                              void* d_out, int out_size, void* d_ws, size_t ws_size,
                              hipStream_t stream) {
    const float* x   = (const float*)d_in[0];
    const int*   eb  = (const int*)d_in[1];
    const float* W1a = (const float*)d_in[2];
    const float* b1a = (const float*)d_in[3];
    const float* W1b = (const float*)d_in[4];
    const float* b1b = (const float*)d_in[5];
    const float* g1  = (const float*)d_in[6];
    const float* be1 = (const float*)d_in[7];
    const float* W2a = (const float*)d_in[8];
    const float* b2a = (const float*)d_in[9];
    const float* W2b = (const float*)d_in[10];
    const float* b2b = (const float*)d_in[11];
    const float* g2  = (const float*)d_in[12];
    const float* be2 = (const float*)d_in[13];
    float* out = (float*)d_out;

    const int N = in_sizes[0] / F_IN;  // 100000
    const int E = in_sizes[1] / 2;     // 3200000
    const int NBUCK = (N + 255) >> BSHIFT;  // 391

    char* w = (char*)d_ws;
    size_t off = 0;
    auto alloc = [&](size_t bytes) -> void* {
        void* p = w + off;
        off = (off + bytes + 255) & ~(size_t)255;
        return p;
    };
    ushort* B0 = (ushort*)alloc((size_t)N * H1 * 2);  // s1b -> s2b
    ushort* B1 = (ushort*)alloc((size_t)N * H1 * 2);  // t1b -> t2b
    char*   B2 = (char*)alloc((size_t)N * H1 * 4);    // u1b (bf16) -> u2 (f32)
    ushort* u1b = (ushort*)B2;
    float*  u2  = (float*)B2;

    int* rs2       = (int*)alloc(((size_t)N * 8 + 1) * 4);  // per-(node,octile) starts
    int* esrc      = (int*)alloc((size_t)E * 4);
    uint* rec      = (uint*)alloc((size_t)NBUCK * BCAP * 4);
    int* bucket_cursor = (int*)alloc(512 * 4);
    ushort* w1aT = (ushort*)alloc(F_IN * H1 * 2);
    ushort* w1bT = (ushort*)alloc(H1 * H1 * 2);
    ushort* w2aT = (ushort*)alloc(H1 * H2 * 2);
    ushort* w2bT = (ushort*)alloc(H2 * H2 * 2);
    float* sums1 = (float*)alloc(NSHARD * 2 * H1 * 4);
    float* sums2 = (float*)alloc(NSHARD * 2 * H2 * 4);

    const int GB = (E + CHUNK - 1) / CHUNK;     // 782 binA blocks
    const int G1 = (N + 63) / 64;               // 1563 gemm blocks
    const int HWT = AGG1_GRID * 8;              // 14336 half-waves
    const int NPH = (N + HWT - 1) / HWT;        // 7 nodes per half-wave

    // K0: weight casts + scratch zeroing
    super0_k<<<213, 256, 0, stream>>>(W1a, W1b, W2a, W2b, w1aT, w1bT, w2aT, w2bT,
                                      bucket_cursor, sums1, sums2);
    // K1: CSR phase A (staged)
    binA_k<<<GB, 256, 0, stream>>>(eb, E, N, NBUCK, bucket_cursor, rec);
    // K2: CSR phase B (octile-binned rows) overlapped with gemm1
    super2_k<<<NBUCK + G1, 256, 0, stream>>>(rec, bucket_cursor, N, NBUCK,
                                             rs2, esrc, x, w1aT, B1);
    // K3: s1 = relu(t1 + agg(t1) + b1a)  [grid-resident, 4-phase, 8-deep ILP]
    agg_f128b_k<<<AGG1_GRID, 256, 0, stream>>>(B1, rs2, esrc, b1a, B0, N, NPH);
    // K4: u1 = s1 @ W1b + b1b (bf16 out) + fused column stats
    gemm_mfma_k<H1, H1, true, true, true><<<G1, 256, 0, stream>>>(B0, w1bT, b1b, u1b, N, sums1);
    // K5: t2 = relu(BN(u1)) @ W2a  (finalize + BN-apply fused into A-load)
    gemm_mfma_bnA_k<H1, H2, true><<<G1, 256, 0, stream>>>(u1b, w2aT, sums1, g1, be1, N, B1, N);
    // K6: s2 = relu(t2 + agg(t2) + b2a)
    agg_f32b_k<<<(N + 3) / 4, 256, 0, stream>>>(B1, rs2, esrc, b2a, B0, N);
    // K7: u2 = s2 @ W2b + b2b (f32 out) + fused column stats
    gemm_mfma_k<H2, H2, true, false, true><<<G1, 256, 0, stream>>>(B0, w2bT, b2b, u2, N, sums2);
    // K8: out = relu(BN(u2))  (finalize fused)
    bnapply_fin_k<H2><<<3125, 256, 0, stream>>>(u2, sums2, g2, be2, N, out, N * H2 / 4);
}

// Round 12
// 369.713 us; speedup vs baseline: 1.0348x; 1.0348x over previous
//
#include <hip/hip_runtime.h>

#define F_IN 256
#define H1 128
#define H2 32
#define BN_EPS 1e-5f
#define BSHIFT 8
#define BCAP 16384
#define CHUNK 4096
#define NSHARD 8

typedef short bf16x8 __attribute__((ext_vector_type(8)));
typedef float f32x4 __attribute__((ext_vector_type(4)));

__device__ __forceinline__ ushort f2bf(float f) {
    uint u = __float_as_uint(f);
    return (ushort)((u + 0x7FFFu + ((u >> 16) & 1u)) >> 16);
}
__device__ __forceinline__ float bf2f(ushort h) {
    return __uint_as_float((uint)h << 16);
}
__device__ __forceinline__ uint pack2(float a, float b) {
    return (uint)f2bf(a) | ((uint)f2bf(b) << 16);
}
__device__ __forceinline__ void unpack2(uint u, float& a, float& b) {
    a = __uint_as_float(u << 16);
    b = __uint_as_float(u & 0xFFFF0000u);
}
__device__ __forceinline__ int clampN(int v, int N) {
    return v < 0 ? 0 : (v >= N ? N - 1 : v);
}

// ---------------------------------------------------------------------------
// super0: weight transpose+cast (blocks 0..211) + zero scratch (block 212)
// ---------------------------------------------------------------------------
__global__ __launch_bounds__(256) void super0_k(
    const float* __restrict__ W1a, const float* __restrict__ W1b,
    const float* __restrict__ W2a, const float* __restrict__ W2b,
    ushort* __restrict__ w1aT, ushort* __restrict__ w1bT,
    ushort* __restrict__ w2aT, ushort* __restrict__ w2bT,
    int* __restrict__ bucket_cursor, float* __restrict__ sums1,
    float* __restrict__ sums2) {
    const int tid = threadIdx.x;
    if (blockIdx.x == 212) {
        for (int i = tid; i < 512; i += 256) bucket_cursor[i] = 0;
        for (int i = tid; i < NSHARD * 2 * H1; i += 256) sums1[i] = 0.f;
        for (int i = tid; i < NSHARD * 2 * H2; i += 256) sums2[i] = 0.f;
        return;
    }
    int idx = blockIdx.x * 256 + tid;
    if (idx < 32768) {                // 256x128
        int k = idx >> 7, c = idx & 127;
        w1aT[c * 256 + k] = f2bf(W1a[idx]);
    } else if (idx < 49152) {         // 128x128
        int t = idx - 32768;
        int k = t >> 7, c = t & 127;
        w1bT[c * 128 + k] = f2bf(W1b[t]);
    } else if (idx < 53248) {         // 128x32
        int t = idx - 49152;
        int k = t >> 5, c = t & 31;
        w2aT[c * 128 + k] = f2bf(W2a[t]);
    } else if (idx < 54272) {         // 32x32
        int t = idx - 53248;
        int k = t >> 5, c = t & 31;
        w2bT[c * 32 + k] = f2bf(W2b[t]);
    }
}

// ---------------------------------------------------------------------------
// binA (staged): CHUNK edges through LDS; per-chunk histogram -> one global
// atomic per (chunk,bucket); grouped record writes.
// record = src (17b) | dst_low (8b) << 17.
// ---------------------------------------------------------------------------
__global__ __launch_bounds__(256) void binA_k(const int* __restrict__ eb,
                                              int E, int N, int NBUCK,
                                              int* __restrict__ bucket_cursor,
                                              uint* __restrict__ rec) {
    __shared__ int lcnt[512];
    __shared__ int lbase[512];
    __shared__ uint lrec[CHUNK];
    __shared__ ushort lbk[CHUNK];
    __shared__ ushort lrk[CHUNK];
    __shared__ int nzf;
    const int tid = threadIdx.x;
    const int cbase = blockIdx.x * CHUNK;
    const int cnum = min(CHUNK, E - cbase);
    if (cnum <= 0) return;
    if (tid == 0) nzf = 0;
    __syncthreads();
    {   // sample odd words of this chunk: int64 -> all high halves zero
        int i = tid * (CHUNK / 256);
        if (i < cnum && eb[2 * (cbase + i) + 1] != 0) atomicAdd(&nzf, 1);
    }
    for (int i = tid; i < NBUCK; i += 256) lcnt[i] = 0;
    __syncthreads();
    const int is64 = (nzf == 0);
    for (int i = tid; i < cnum; i += 256) {
        int e = cbase + i;
        int s = is64 ? eb[2 * e] : eb[e];
        int d = is64 ? eb[2 * (E + e)] : eb[E + e];
        s = clampN(s, N);
        d = clampN(d, N);
        int bk = d >> BSHIFT;
        int rk = atomicAdd(&lcnt[bk], 1);
        lrec[i] = (uint)s | ((uint)(d & 255) << 17);
        lbk[i] = (ushort)bk;
        lrk[i] = (ushort)rk;
    }
    __syncthreads();
    for (int i = tid; i < NBUCK; i += 256)
        if (lcnt[i]) lbase[i] = atomicAdd(&bucket_cursor[i], lcnt[i]);
    __syncthreads();
    for (int i = tid; i < cnum; i += 256) {
        int bk = lbk[i];
        int pos = lbase[bk] + lrk[i];
        if (pos < BCAP) rec[(size_t)bk * BCAP + pos] = lrec[i];
    }
}

// ---------------------------------------------------------------------------
// binB body: one block per dst-bucket. Bins records by (dst_low, src-octile)
// = 2048 bins -> LDS scan -> rs2 boundaries + esrc grouped by (node, octile)
// => within each node's row, esrc is octile-sorted (ascending src granule).
// ---------------------------------------------------------------------------
__device__ __forceinline__ void binB_body(int bk, const uint* __restrict__ rec,
                                          const int* __restrict__ bucket_cursor,
                                          int N, int NBUCK,
                                          int* __restrict__ rs2,
                                          int* __restrict__ esrc) {
    __shared__ int cnt[2048];
    __shared__ int rnk[2048];
    __shared__ int red[256];
    const int tid = threadIdx.x;
    int part = 0;
    for (int i = tid; i < bk; i += 256) {
        int c = bucket_cursor[i];
        part += (c < BCAP) ? c : BCAP;
    }
    red[tid] = part;
    __syncthreads();
    for (int s = 128; s > 0; s >>= 1) {
        if (tid < s) red[tid] += red[tid + s];
        __syncthreads();
    }
    const int base = red[0];
    __syncthreads();
    int cntb = bucket_cursor[bk];
    if (cntb > BCAP) cntb = BCAP;
    if (bk == NBUCK - 1 && tid == 0) rs2[(size_t)N * 8] = base + cntb;

    const uint* r = rec + (size_t)bk * BCAP;
    for (int i = tid; i < 2048; i += 256) { cnt[i] = 0; rnk[i] = 0; }
    __syncthreads();
    for (int i = tid; i < cntb; i += 256) {
        uint rv = r[i];
        atomicAdd(&cnt[((rv >> 17) << 3) | ((rv >> 14) & 7u)], 1);
    }
    __syncthreads();
    int loc[8];
    int s = 0;
#pragma unroll
    for (int j = 0; j < 8; ++j) { loc[j] = s; s += cnt[tid * 8 + j]; }
    const int tot = s;
    red[tid] = tot;
    __syncthreads();
    for (int off = 1; off < 256; off <<= 1) {
        int t = (tid >= off) ? red[tid - off] : 0;
        __syncthreads();
        red[tid] += t;
        __syncthreads();
    }
    const int excl_t = red[tid] - tot;
    __syncthreads();
    const int n0 = bk << BSHIFT;
#pragma unroll
    for (int j = 0; j < 8; ++j) {
        int b = tid * 8 + j;
        int ex = excl_t + loc[j];
        cnt[b] = ex;
        int node = n0 + (b >> 3);
        if (node < N) rs2[(size_t)node * 8 + (b & 7)] = base + ex;
    }
    __syncthreads();
    for (int i = tid; i < cntb; i += 256) {
        uint rv = r[i];
        int b = ((rv >> 17) << 3) | ((rv >> 14) & 7u);
        int pos = cnt[b] + atomicAdd(&rnk[b], 1);
        esrc[base + pos] = (int)(rv & 0x1FFFFu);
    }
}

// ---------------------------------------------------------------------------
// gemm1 body: t1 = x(f32, packed in-register) @ W1aT, bf16 out. No LDS.
// ---------------------------------------------------------------------------
__device__ __forceinline__ void gemm1_body(int bid, const float* __restrict__ Af,
                                           const ushort* __restrict__ WT,
                                           ushort* __restrict__ outb, int N) {
    constexpr int K = F_IN, NC = H1, NF = NC / 16;
    const int lane = threadIdx.x & 63;
    const int wave = threadIdx.x >> 6;
    const int row0 = bid * 64 + wave * 16;
    const int col = lane & 15;
    const int k0 = (lane >> 4) * 8;
    int arow = row0 + col;
    if (arow >= N) arow = N - 1;

    f32x4 acc[NF];
#pragma unroll
    for (int f = 0; f < NF; ++f) acc[f] = (f32x4){0.f, 0.f, 0.f, 0.f};
#pragma unroll
    for (int kc = 0; kc < K; kc += 32) {
        const float* ap = &Af[(size_t)arow * K + kc + k0];
        float4 p = *(const float4*)ap;
        float4 q = *(const float4*)(ap + 4);
        bf16x8 af;
        af[0] = (short)f2bf(p.x); af[1] = (short)f2bf(p.y);
        af[2] = (short)f2bf(p.z); af[3] = (short)f2bf(p.w);
        af[4] = (short)f2bf(q.x); af[5] = (short)f2bf(q.y);
        af[6] = (short)f2bf(q.z); af[7] = (short)f2bf(q.w);
#pragma unroll
        for (int f = 0; f < NF; ++f) {
            bf16x8 bf = *(const bf16x8*)&WT[(size_t)(f * 16 + col) * K + kc + k0];
            acc[f] = __builtin_amdgcn_mfma_f32_16x16x32_bf16(af, bf, acc[f], 0, 0, 0);
        }
    }
    const int crow = row0 + (lane >> 4) * 4;
#pragma unroll
    for (int f = 0; f < NF; ++f) {
        const int c = f * 16 + col;
#pragma unroll
        for (int j = 0; j < 4; ++j) {
            int rr = crow + j;
            if (rr < N) outb[(size_t)rr * NC + c] = f2bf(acc[f][j]);
        }
    }
}

// super2: binB blocks [0, NBUCK) overlap gemm1 blocks [NBUCK, NBUCK+G1).
__global__ __launch_bounds__(256) void super2_k(
    const uint* __restrict__ rec, const int* __restrict__ bucket_cursor,
    int N, int NBUCK, int* __restrict__ rs2, int* __restrict__ esrc,
    const float* __restrict__ x, const ushort* __restrict__ w1aT,
    ushort* __restrict__ t1b) {
    if ((int)blockIdx.x < NBUCK)
        binB_body(blockIdx.x, rec, bucket_cursor, N, NBUCK, rs2, esrc);
    else
        gemm1_body(blockIdx.x - NBUCK, x, w1aT, t1b, N);
}

// ---------------------------------------------------------------------------
// shared GEMM epilogue: store + optional fused column stats
// ---------------------------------------------------------------------------
template <int NC, bool BIAS, bool OUT_BF16, bool STATS, int NF>
__device__ __forceinline__ void gemm_epilogue(f32x4* acc, const float* bias,
                                              void* outv, int N, int row0,
                                              int lane, float* sums) {
    __shared__ float ssum[NC];
    __shared__ float ssq[NC];
    if (STATS) {
        if (threadIdx.x < NC) { ssum[threadIdx.x] = 0.f; ssq[threadIdx.x] = 0.f; }
        __syncthreads();
    }
    const int col0 = lane & 15;
    const int crow = row0 + (lane >> 4) * 4;
#pragma unroll
    for (int f = 0; f < NF; ++f) {
        const int c = f * 16 + col0;
        float bv = BIAS ? bias[c] : 0.f;
        float sv = 0.f, qv = 0.f;
#pragma unroll
        for (int j = 0; j < 4; ++j) {
            int rr = crow + j;
            if (rr < N) {
                float v = acc[f][j] + bv;
                if (OUT_BF16) ((ushort*)outv)[(size_t)rr * NC + c] = f2bf(v);
                else          ((float*)outv)[(size_t)rr * NC + c] = v;
                if (STATS) { sv += v; qv += v * v; }
            }
        }
        if (STATS) {
            sv += __shfl_xor(sv, 16); sv += __shfl_xor(sv, 32);
            qv += __shfl_xor(qv, 16); qv += __shfl_xor(qv, 32);
            if ((lane >> 4) == 0) {
                atomicAdd(&ssum[c], sv);
                atomicAdd(&ssq[c], qv);
            }
        }
    }
    if (STATS) {
        __syncthreads();
        if (threadIdx.x < NC) {
            float* sh = sums + (blockIdx.x & (NSHARD - 1)) * 2 * NC;
            atomicAdd(&sh[threadIdx.x], ssum[threadIdx.x]);
            atomicAdd(&sh[NC + threadIdx.x], ssq[threadIdx.x]);
        }
    }
}

// MFMA GEMM, bf16 A: out[N,NC] = A[N,K] @ WT[NC,K]^T (+bias) [+col stats]
template <int K, int NC, bool BIAS, bool OUT_BF16, bool STATS>
__global__ __launch_bounds__(256) void gemm_mfma_k(const ushort* __restrict__ A,
                                                   const ushort* __restrict__ WT,
                                                   const float* __restrict__ bias,
                                                   void* __restrict__ outv, int N,
                                                   float* __restrict__ sums) {
    constexpr int NF = NC / 16;
    const int lane = threadIdx.x & 63;
    const int wave = threadIdx.x >> 6;
    const int row0 = blockIdx.x * 64 + wave * 16;
    const int col = lane & 15;
    const int k0 = (lane >> 4) * 8;
    int arow = row0 + col;
    if (arow >= N) arow = N - 1;

    f32x4 acc[NF];
#pragma unroll
    for (int f = 0; f < NF; ++f) acc[f] = (f32x4){0.f, 0.f, 0.f, 0.f};
#pragma unroll
    for (int kc = 0; kc < K; kc += 32) {
        bf16x8 af = *(const bf16x8*)&A[(size_t)arow * K + kc + k0];
#pragma unroll
        for (int f = 0; f < NF; ++f) {
            bf16x8 bf = *(const bf16x8*)&WT[(size_t)(f * 16 + col) * K + kc + k0];
            acc[f] = __builtin_amdgcn_mfma_f32_16x16x32_bf16(af, bf, acc[f], 0, 0, 0);
        }
    }
    gemm_epilogue<NC, BIAS, OUT_BF16, STATS, NF>(acc, bias, outv, N, row0, lane, sums);
}

// MFMA GEMM with fused BN finalize (from sharded sums) + BN-apply+ReLU on A
template <int K, int NC, bool OUT_BF16>
__global__ __launch_bounds__(256) void gemm_mfma_bnA_k(const ushort* __restrict__ U,
                                                       const ushort* __restrict__ WT,
                                                       const float* __restrict__ sums,
                                                       const float* __restrict__ g,
                                                       const float* __restrict__ be,
                                                       int Nbn,
                                                       void* __restrict__ outv, int N) {
    constexpr int NF = NC / 16;
    __shared__ __align__(16) float lsc[K];
    __shared__ __align__(16) float lsh[K];
    const int tid = threadIdx.x;
    if (tid < K) {
        float s = 0.f, q = 0.f;
#pragma unroll
        for (int sh = 0; sh < NSHARD; ++sh) {
            s += sums[sh * 2 * K + tid];
            q += sums[sh * 2 * K + K + tid];
        }
        float inv_n = 1.f / (float)Nbn;
        float mean = s * inv_n;
        float var = q * inv_n - mean * mean;
        float sc = g[tid] * rsqrtf(var + BN_EPS);
        lsc[tid] = sc;
        lsh[tid] = be[tid] - mean * sc;
    }
    __syncthreads();

    const int lane = tid & 63;
    const int wave = tid >> 6;
    const int row0 = blockIdx.x * 64 + wave * 16;
    const int col = lane & 15;
    const int k0 = (lane >> 4) * 8;
    int arow = row0 + col;
    if (arow >= N) arow = N - 1;

    f32x4 acc[NF];
#pragma unroll
    for (int f = 0; f < NF; ++f) acc[f] = (f32x4){0.f, 0.f, 0.f, 0.f};
#pragma unroll
    for (int kc = 0; kc < K; kc += 32) {
        bf16x8 raw = *(const bf16x8*)&U[(size_t)arow * K + kc + k0];
        float4 c0 = *(const float4*)&lsc[kc + k0];
        float4 c1 = *(const float4*)&lsc[kc + k0 + 4];
        float4 h0 = *(const float4*)&lsh[kc + k0];
        float4 h1 = *(const float4*)&lsh[kc + k0 + 4];
        bf16x8 af;
        af[0] = (short)f2bf(fmaxf(bf2f((ushort)raw[0]) * c0.x + h0.x, 0.f));
        af[1] = (short)f2bf(fmaxf(bf2f((ushort)raw[1]) * c0.y + h0.y, 0.f));
        af[2] = (short)f2bf(fmaxf(bf2f((ushort)raw[2]) * c0.z + h0.z, 0.f));
        af[3] = (short)f2bf(fmaxf(bf2f((ushort)raw[3]) * c0.w + h0.w, 0.f));
        af[4] = (short)f2bf(fmaxf(bf2f((ushort)raw[4]) * c1.x + h1.x, 0.f));
        af[5] = (short)f2bf(fmaxf(bf2f((ushort)raw[5]) * c1.y + h1.y, 0.f));
        af[6] = (short)f2bf(fmaxf(bf2f((ushort)raw[6]) * c1.z + h1.z, 0.f));
        af[7] = (short)f2bf(fmaxf(bf2f((ushort)raw[7]) * c1.w + h1.w, 0.f));
#pragma unroll
        for (int f = 0; f < NF; ++f) {
            bf16x8 bf = *(const bf16x8*)&WT[(size_t)(f * 16 + col) * K + kc + k0];
            acc[f] = __builtin_amdgcn_mfma_f32_16x16x32_bf16(af, bf, acc[f], 0, 0, 0);
        }
    }
    gemm_epilogue<NC, false, OUT_BF16, false, NF>(acc, nullptr, outv, N, row0, lane, nullptr);
}

// ---------------------------------------------------------------------------
// fused aggregation (flat row, 8-deep cascade — measured-best R10 form):
// out = relu(T[i] + sum_j T[j] + bias). F=128: half-wave per node, x8 unroll.
// ---------------------------------------------------------------------------
__global__ void agg_f128b_k(const ushort* __restrict__ T, const int* __restrict__ rs2,
                            const int* __restrict__ esrc, const float* __restrict__ bias,
                            ushort* __restrict__ out, int N) {
    const int hw = (blockIdx.x << 3) | (threadIdx.x >> 5);
    const int lane = threadIdx.x & 31;
    if (hw >= N) return;
    const uint2* T2 = (const uint2*)T;
    uint2 sv = T2[(size_t)hw * 32 + lane];
    float a0, a1, a2, a3;
    unpack2(sv.x, a0, a1);
    unpack2(sv.y, a2, a3);
    int p = rs2[(size_t)hw * 8];
    const int pe = rs2[(size_t)hw * 8 + 8];
    for (; p + 7 < pe; p += 8) {
        int s0 = esrc[p],     s1 = esrc[p + 1], s2 = esrc[p + 2], s3 = esrc[p + 3];
        int s4 = esrc[p + 4], s5 = esrc[p + 5], s6 = esrc[p + 6], s7 = esrc[p + 7];
        uint2 v0 = T2[(size_t)s0 * 32 + lane];
        uint2 v1 = T2[(size_t)s1 * 32 + lane];
        uint2 v2 = T2[(size_t)s2 * 32 + lane];
        uint2 v3 = T2[(size_t)s3 * 32 + lane];
        uint2 v4 = T2[(size_t)s4 * 32 + lane];
        uint2 v5 = T2[(size_t)s5 * 32 + lane];
        uint2 v6 = T2[(size_t)s6 * 32 + lane];
        uint2 v7 = T2[(size_t)s7 * 32 + lane];
        float x0, x1, x2, x3;
        unpack2(v0.x, x0, x1); unpack2(v0.y, x2, x3);
        a0 += x0; a1 += x1; a2 += x2; a3 += x3;
        unpack2(v1.x, x0, x1); unpack2(v1.y, x2, x3);
        a0 += x0; a1 += x1; a2 += x2; a3 += x3;
        unpack2(v2.x, x0, x1); unpack2(v2.y, x2, x3);
        a0 += x0; a1 += x1; a2 += x2; a3 += x3;
        unpack2(v3.x, x0, x1); unpack2(v3.y, x2, x3);
        a0 += x0; a1 += x1; a2 += x2; a3 += x3;
        unpack2(v4.x, x0, x1); unpack2(v4.y, x2, x3);
        a0 += x0; a1 += x1; a2 += x2; a3 += x3;
        unpack2(v5.x, x0, x1); unpack2(v5.y, x2, x3);
        a0 += x0; a1 += x1; a2 += x2; a3 += x3;
        unpack2(v6.x, x0, x1); unpack2(v6.y, x2, x3);
        a0 += x0; a1 += x1; a2 += x2; a3 += x3;
        unpack2(v7.x, x0, x1); unpack2(v7.y, x2, x3);
        a0 += x0; a1 += x1; a2 += x2; a3 += x3;
    }
    for (; p < pe; ++p) {
        uint2 v = T2[(size_t)esrc[p] * 32 + lane];
        float x0, x1, x2, x3;
        unpack2(v.x, x0, x1); unpack2(v.y, x2, x3);
        a0 += x0; a1 += x1; a2 += x2; a3 += x3;
    }
    const float4 b = ((const float4*)bias)[lane];
    a0 = fmaxf(a0 + b.x, 0.f);
    a1 = fmaxf(a1 + b.y, 0.f);
    a2 = fmaxf(a2 + b.z, 0.f);
    a3 = fmaxf(a3 + b.w, 0.f);
    ((uint2*)out)[(size_t)hw * 32 + lane] = make_uint2(pack2(a0, a1), pack2(a2, a3));
}

// F=32: wave per node; 8 neighbor-groups x 8 lanes; cross-group shfl reduce.
__global__ void agg_f32b_k(const ushort* __restrict__ T, const int* __restrict__ rs2,
                           const int* __restrict__ esrc, const float* __restrict__ bias,
                           ushort* __restrict__ out, int N) {
    const int wid = (blockIdx.x << 2) | (threadIdx.x >> 6);
    const int lane = threadIdx.x & 63;
    const int g = lane >> 3, l8 = lane & 7;
    if (wid >= N) return;
    const uint2* T2 = (const uint2*)T;
    float a0 = 0.f, a1 = 0.f, a2 = 0.f, a3 = 0.f;
    const int p0 = rs2[(size_t)wid * 8];
    const int pe = rs2[(size_t)wid * 8 + 8];
    for (int p = p0 + g; p < pe; p += 8) {
        uint2 v = T2[(size_t)esrc[p] * 8 + l8];
        float x0, x1, x2, x3;
        unpack2(v.x, x0, x1); unpack2(v.y, x2, x3);
        a0 += x0; a1 += x1; a2 += x2; a3 += x3;
    }
#pragma unroll
    for (int off = 8; off < 64; off <<= 1) {
        a0 += __shfl_xor(a0, off);
        a1 += __shfl_xor(a1, off);
        a2 += __shfl_xor(a2, off);
        a3 += __shfl_xor(a3, off);
    }
    if (g == 0) {
        uint2 sv = T2[(size_t)wid * 8 + l8];
        float s0, s1, s2, s3;
        unpack2(sv.x, s0, s1); unpack2(sv.y, s2, s3);
        const float4 b = ((const float4*)bias)[l8];
        a0 = fmaxf(a0 + s0 + b.x, 0.f);
        a1 = fmaxf(a1 + s1 + b.y, 0.f);
        a2 = fmaxf(a2 + s2 + b.z, 0.f);
        a3 = fmaxf(a3 + s3 + b.w, 0.f);
        ((uint2*)out)[(size_t)wid * 8 + l8] = make_uint2(pack2(a0, a1), pack2(a2, a3));
    }
}

// ---------------------------------------------------------------------------
// bnapply with fused finalize (from sharded sums): f32 in -> f32 out
// ---------------------------------------------------------------------------
template <int F>
__global__ void bnapply_fin_k(const float* __restrict__ U, const float* __restrict__ sums,
                              const float* __restrict__ g, const float* __restrict__ be,
                              int Nbn, float* __restrict__ out, int total4) {
    __shared__ __align__(16) float lsc[F];
    __shared__ __align__(16) float lsh[F];
    const int tid = threadIdx.x;
    if (tid < F) {
        float s = 0.f, q = 0.f;
#pragma unroll
        for (int sh = 0; sh < NSHARD; ++sh) {
            s += sums[sh * 2 * F + tid];
            q += sums[sh * 2 * F + F + tid];
        }
        float inv_n = 1.f / (float)Nbn;
        float mean = s * inv_n;
        float var = q * inv_n - mean * mean;
        float sc = g[tid] * rsqrtf(var + BN_EPS);
        lsc[tid] = sc;
        lsh[tid] = be[tid] - mean * sc;
    }
    __syncthreads();
    const float4* U4 = (const float4*)U;
    float4* O4 = (float4*)out;
    const int stride = gridDim.x * blockDim.x;
    for (int i = blockIdx.x * blockDim.x + tid; i < total4; i += stride) {
        int c4 = (i % (F / 4)) * 4;
        float4 u = U4[i];
        float4 sc = *(const float4*)&lsc[c4];
        float4 sh = *(const float4*)&lsh[c4];
        float4 o;
        o.x = fmaxf(u.x * sc.x + sh.x, 0.f);
        o.y = fmaxf(u.y * sc.y + sh.y, 0.f);
        o.z = fmaxf(u.z * sc.z + sh.z, 0.f);
        o.w = fmaxf(u.w * sc.w + sh.w, 0.f);
        O4[i] = o;
    }
}

// ---------------------------------------------------------------------------
extern "C" void kernel_launch(void* const* d_in, const int* in_sizes, int n_in,
                              void* d_out, int out_size, void* d_ws, size_t ws_size,
                              hipStream_t stream) {
    const float* x   = (const float*)d_in[0];
    const int*   eb  = (const int*)d_in[1];
    const float* W1a = (const float*)d_in[2];
    const float* b1a = (const float*)d_in[3];
    const float* W1b = (const float*)d_in[4];
    const float* b1b = (const float*)d_in[5];
    const float* g1  = (const float*)d_in[6];
    const float* be1 = (const float*)d_in[7];
    const float* W2a = (const float*)d_in[8];
    const float* b2a = (const float*)d_in[9];
    const float* W2b = (const float*)d_in[10];
    const float* b2b = (const float*)d_in[11];
    const float* g2  = (const float*)d_in[12];
    const float* be2 = (const float*)d_in[13];
    float* out = (float*)d_out;

    const int N = in_sizes[0] / F_IN;  // 100000
    const int E = in_sizes[1] / 2;     // 3200000
    const int NBUCK = (N + 255) >> BSHIFT;  // 391

    char* w = (char*)d_ws;
    size_t off = 0;
    auto alloc = [&](size_t bytes) -> void* {
        void* p = w + off;
        off = (off + bytes + 255) & ~(size_t)255;
        return p;
    };
    ushort* B0 = (ushort*)alloc((size_t)N * H1 * 2);  // s1b -> s2b
    ushort* B1 = (ushort*)alloc((size_t)N * H1 * 2);  // t1b -> t2b
    char*   B2 = (char*)alloc((size_t)N * H1 * 4);    // u1b (bf16) -> u2 (f32)
    ushort* u1b = (ushort*)B2;
    float*  u2  = (float*)B2;

    int* rs2       = (int*)alloc(((size_t)N * 8 + 1) * 4);  // per-(node,octile) starts
    int* esrc      = (int*)alloc((size_t)E * 4);
    uint* rec      = (uint*)alloc((size_t)NBUCK * BCAP * 4);
    int* bucket_cursor = (int*)alloc(512 * 4);
    ushort* w1aT = (ushort*)alloc(F_IN * H1 * 2);
    ushort* w1bT = (ushort*)alloc(H1 * H1 * 2);
    ushort* w2aT = (ushort*)alloc(H1 * H2 * 2);
    ushort* w2bT = (ushort*)alloc(H2 * H2 * 2);
    float* sums1 = (float*)alloc(NSHARD * 2 * H1 * 4);
    float* sums2 = (float*)alloc(NSHARD * 2 * H2 * 4);

    const int GB = (E + CHUNK - 1) / CHUNK;     // 782 binA blocks
    const int G1 = (N + 63) / 64;               // 1563 gemm blocks

    // K0: weight casts + scratch zeroing
    super0_k<<<213, 256, 0, stream>>>(W1a, W1b, W2a, W2b, w1aT, w1bT, w2aT, w2bT,
                                      bucket_cursor, sums1, sums2);
    // K1: CSR phase A (staged)
    binA_k<<<GB, 256, 0, stream>>>(eb, E, N, NBUCK, bucket_cursor, rec);
    // K2: CSR phase B (octile-binned rows) overlapped with gemm1
    super2_k<<<NBUCK + G1, 256, 0, stream>>>(rec, bucket_cursor, N, NBUCK,
                                             rs2, esrc, x, w1aT, B1);
    // K3: s1 = relu(t1 + agg(t1) + b1a)  [R7 loop, octile-sorted rows]
    agg_f128b_k<<<(N + 7) / 8, 256, 0, stream>>>(B1, rs2, esrc, b1a, B0, N);
    // K4: u1 = s1 @ W1b + b1b (bf16 out) + fused column stats
    gemm_mfma_k<H1, H1, true, true, true><<<G1, 256, 0, stream>>>(B0, w1bT, b1b, u1b, N, sums1);
    // K5: t2 = relu(BN(u1)) @ W2a  (finalize + BN-apply fused into A-load)
    gemm_mfma_bnA_k<H1, H2, true><<<G1, 256, 0, stream>>>(u1b, w2aT, sums1, g1, be1, N, B1, N);
    // K6: s2 = relu(t2 + agg(t2) + b2a)
    agg_f32b_k<<<(N + 3) / 4, 256, 0, stream>>>(B1, rs2, esrc, b2a, B0, N);
    // K7: u2 = s2 @ W2b + b2b (f32 out) + fused column stats
    gemm_mfma_k<H2, H2, true, false, true><<<G1, 256, 0, stream>>>(B0, w2bT, b2b, u2, N, sums2);
    // K8: out = relu(BN(u2))  (finalize fused)
    bnapply_fin_k<H2><<<3125, 256, 0, stream>>>(u2, sums2, g2, be2, N, out, N * H2 / 4);
}